// Round 14
// baseline (458.752 us; speedup 1.0000x reference)
//
#include <hip/hip_runtime.h>
#include <math.h>

#define N_  8
#define C_  19
#define H_  512
#define W_  1024
#define HW_ (H_ * W_)          // 524288
#define NPIX (N_ * HW_)        // 4194304
#define IGNORE_IDX 255
#define LOSS_BLOCKS 4096

// Workspace layout:
//   [0,    608)   int    hist[N_][C_]      (152 ints)   -- zeroed
//   [608,  612)   int    valid_count                    -- zeroed
//   [1024, 33792) double part[LOSS_BLOCKS]              -- fully written by loss_kernel
#define WS_HIST_OFF   0
#define WS_VALID_OFF  608
#define WS_PART_OFF   1024
#define WS_ZERO_BYTES 1024

// ---------------------------------------------------------------------------
// Kernel 1: per-sample class histogram + valid count, ballot-popcount style.
// (unchanged from R8 — measured-good)
// ---------------------------------------------------------------------------
__global__ __launch_bounds__(256) void hist_kernel(
    const int* __restrict__ tgt, int* __restrict__ hist, int* __restrict__ valid_cnt) {
  __shared__ int lh[C_];
  __shared__ int lvalid;
  const int tid = threadIdx.x;
  if (tid < C_) lh[tid] = 0;
  if (tid == 0) lvalid = 0;
  __syncthreads();

  const int n = blockIdx.x >> 6;     // 64 blocks per sample
  const int seg = blockIdx.x & 63;   // 2048 int4 per block
  const int4* tp = reinterpret_cast<const int4*>(tgt) +
                   (size_t)n * (HW_ / 4) + (size_t)seg * 2048;

  int cnt[C_];
#pragma unroll
  for (int c = 0; c < C_; ++c) cnt[c] = 0;
  int vcnt = 0;

#pragma unroll
  for (int it = 0; it < 8; ++it) {
    const int4 t4 = tp[it * 256 + tid];
    const int tv[4] = {t4.x, t4.y, t4.z, t4.w};
#pragma unroll
    for (int j = 0; j < 4; ++j) {
      vcnt += (int)__popcll(__ballot(tv[j] != IGNORE_IDX));
#pragma unroll
      for (int c = 0; c < C_; ++c)
        cnt[c] += (int)__popcll(__ballot(tv[j] == c));
    }
  }

  if ((tid & 63) == 0) {
#pragma unroll
    for (int c = 0; c < C_; ++c)
      if (cnt[c]) atomicAdd(&lh[c], cnt[c]);
    atomicAdd(&lvalid, vcnt);
  }
  __syncthreads();
  if (tid < C_ && lh[tid]) atomicAdd(&hist[n * C_ + tid], lh[tid]);
  if (tid == 0 && lvalid) atomicAdd(valid_cnt, lvalid);
}

// ---------------------------------------------------------------------------
// Kernel 2: fused online log-softmax + weighted NLL partial sum.
// CHANGE vs R8 (in flight, unmeasured): 4 pixels/thread (ONE float4 stream),
// 4096 blocks. Rationale: the 8-px/2-stream body kept ~38 live 64-bit channel
// addresses (2 MB stride can't fold into the 13-bit load offset) -> VGPR>64
// suspected -> 4 waves/SIMD -> HBM latency (~900cy) not covered. Halving
// per-thread state targets VGPR<=64 -> 8 waves/SIMD, 2x TLP.
// ---------------------------------------------------------------------------
__global__ __launch_bounds__(256) void loss_kernel(
    const float* __restrict__ x, const int* __restrict__ tgt,
    const int* __restrict__ hist, double* __restrict__ part) {
  __shared__ float lw[C_];
  const int tid = threadIdx.x;
  const int n = blockIdx.x >> 9;   // 512 blocks per sample

  // Per-sample class weights: w[c] = sum_c' max(h,1) / max(h[c],1)  (RATIO=1)
  if (tid < C_) {
    int s = 0;
#pragma unroll
    for (int c = 0; c < C_; ++c) s += max(hist[n * C_ + c], 1);
    lw[tid] = (float)s / (float)max(hist[n * C_ + tid], 1);
  }
  __syncthreads();

  const int blk = blockIdx.x & 511;       // block's slice within sample
  const int q0 = blk * 256 + tid;         // float4 index within sample
  const float* xb = x + (size_t)n * C_ * HW_;

  // Targets for the 4 pixels.
  const int4 ta = reinterpret_cast<const int4*>(tgt + (size_t)n * HW_)[q0];
  const int t[4] = {ta.x, ta.y, ta.z, ta.w};
  bool val[4];
  int tc[4];
#pragma unroll
  for (int j = 0; j < 4; ++j) {
    val[j] = (t[j] != IGNORE_IDX);
    tc[j] = val[j] ? min(max(t[j], 0), C_ - 1) : 0;
  }

  float m[4], s[4], xt[4];
#pragma unroll
  for (int j = 0; j < 4; ++j) {
    m[j] = -INFINITY;
    s[j] = 0.f;
    xt[j] = 0.f;
  }

#pragma unroll
  for (int c = 0; c < C_; ++c) {
    const float4 va =
        reinterpret_cast<const float4*>(xb + (size_t)c * HW_)[q0];
    const float v[4] = {va.x, va.y, va.z, va.w};
#pragma unroll
    for (int j = 0; j < 4; ++j) {
      const float nm = fmaxf(m[j], v[j]);
      s[j] = s[j] * __expf(m[j] - nm) + __expf(v[j] - nm);
      m[j] = nm;
      xt[j] = (c == tc[j]) ? v[j] : xt[j];
    }
  }

  double acc = 0.0;
#pragma unroll
  for (int j = 0; j < 4; ++j) {
    const float lse = m[j] + __logf(s[j]);
    acc += val[j] ? (double)((lse - xt[j]) * lw[tc[j]]) : 0.0;
  }

  // Wave reduce (64 lanes) then cross-wave via LDS; block leader writes its
  // private partial slot (no global atomic — R12 measured -16us vs atomic).
#pragma unroll
  for (int off = 32; off > 0; off >>= 1) acc += __shfl_down(acc, off, 64);
  __shared__ double wsum[4];
  const int wid = tid >> 6, lane = tid & 63;
  if (lane == 0) wsum[wid] = acc;
  __syncthreads();
  if (tid == 0) part[blockIdx.x] = wsum[0] + wsum[1] + wsum[2] + wsum[3];
}

// ---------------------------------------------------------------------------
// Kernel 3: reduce 4096 block partials + finalize (1 block, 256 threads).
// ---------------------------------------------------------------------------
__global__ __launch_bounds__(256) void finalize_kernel(
    const double* __restrict__ part, const int* __restrict__ valid_cnt,
    float* __restrict__ out) {
  const int tid = threadIdx.x;
  double a = 0.0;
#pragma unroll
  for (int i = 0; i < LOSS_BLOCKS / 256; ++i) a += part[i * 256 + tid];
#pragma unroll
  for (int off = 32; off > 0; off >>= 1) a += __shfl_down(a, off, 64);
  __shared__ double ws[4];
  const int wid = tid >> 6, lane = tid & 63;
  if (lane == 0) ws[wid] = a;
  __syncthreads();
  if (tid == 0) {
    const double s = ws[0] + ws[1] + ws[2] + ws[3];
    const double denom = fmax((double)valid_cnt[0], 1.0);
    out[0] = (float)(s / denom);
  }
}

extern "C" void kernel_launch(void* const* d_in, const int* in_sizes, int n_in,
                              void* d_out, int out_size, void* d_ws, size_t ws_size,
                              hipStream_t stream) {
  const float* inputs = (const float*)d_in[0];
  const int* targets = (const int*)d_in[1];
  float* out = (float*)d_out;

  int* hist = (int*)((char*)d_ws + WS_HIST_OFF);
  int* valid_cnt = (int*)((char*)d_ws + WS_VALID_OFF);
  double* part = (double*)((char*)d_ws + WS_PART_OFF);

  hipMemsetAsync(d_ws, 0, WS_ZERO_BYTES, stream);

  hist_kernel<<<512, 256, 0, stream>>>(targets, hist, valid_cnt);

  // 4194304 pixels / 4 per thread / 256 per block = 4096 blocks (512/sample)
  loss_kernel<<<LOSS_BLOCKS, 256, 0, stream>>>(inputs, targets, hist, part);

  finalize_kernel<<<1, 256, 0, stream>>>(part, valid_cnt, out);
}